// Round 10
// baseline (65.881 us; speedup 1.0000x reference)
//
#include <hip/hip_runtime.h>

// Fused tanh-RNN (T=64, I=64, H=100) + tanh + linear (C=40), B=16384.
// TRANSPOSED formulation: D = A*B, A = register-resident weight fragments,
// B = data^T (x / h). W_hh/fc_W columns pre-permuted by
//   phi(kb,g,e) = 16*(2kb + (e&1)) + 4g + (e>>1)
// and W_ih by phi_ih(kb,g,e) = 32kb + 8g + (e>>1) + 4*(e&1),
// chosen so EVERY packed half2 of a B-fragment is one v_cvt_pkrtz_f16_f32 of
// two accumulator (or two x) f32 values: MFMA D regs -> next step's B-frag via
// 16 pkrtz (h) + 8 pkrtz (x) instead of 44 cvt + 22 pack.
//
// Round-10 = round-9 with the pkrtz return-type fix (__fp16 vec2 -> bit_cast
// to u32; pack4 takes u32s). No semantic change vs the r9 intent:
//  1. pkrtz packing with interleaved phi (same load addresses, new placement).
//  2. ds_read asm split: issue 4x ds_read_b128, run the 28 register-fed whh
//     MFMAs, THEN s_waitcnt lgkmcnt(0) (+sched_barrier) before x-dependent work.

typedef _Float16 half8 __attribute__((ext_vector_type(8)));
typedef float float4_t __attribute__((ext_vector_type(4)));
typedef unsigned int uint4_t __attribute__((ext_vector_type(4)));

#define ROW_BYTES 1088                  // 1024 data + 64 pad
#define BUF_BYTES (16 * ROW_BYTES)      // 17408 per slab buffer
#define GLOAD16(gp, lp)                                                   \
  __builtin_amdgcn_global_load_lds(                                       \
      (const __attribute__((address_space(1))) void*)(gp),                \
      (__attribute__((address_space(3))) void*)(lp), 16, 0, 0)

__device__ __forceinline__ float tanh_fast(float x) {
  float e = __builtin_amdgcn_exp2f(x * 2.8853900817779268f);
  return 1.0f - 2.0f * __builtin_amdgcn_rcpf(e + 1.0f);
}

// v_cvt_pkrtz_f16_f32(lo,hi) -> packed u32
__device__ __forceinline__ unsigned int pk2(float lo, float hi) {
  return __builtin_bit_cast(unsigned int, __builtin_amdgcn_cvt_pkrtz(lo, hi));
}

__device__ __forceinline__ half8 pack4(unsigned int a, unsigned int b,
                                       unsigned int c, unsigned int d) {
  uint4_t u = {a, b, c, d};
  return __builtin_bit_cast(half8, u);
}

// Issue one slab: row j's bytes [slab*1024, +1024) -> buf + j*1088.
__device__ __forceinline__ void issue_slab(const float* srcl, int slab, char* buf) {
  const float* s = srcl + slab * 256;
  #pragma unroll
  for (int j = 0; j < 16; ++j) {
    GLOAD16(s, buf + j * ROW_BYTES);
    s += 4096;
  }
}

__global__ __launch_bounds__(64, 1) void rnn_fused(
    const float* __restrict__ x, const float* __restrict__ W_ih,
    const float* __restrict__ W_hh, const float* __restrict__ b_ih,
    const float* __restrict__ b_hh, const float* __restrict__ fc_W,
    const float* __restrict__ fc_b, float* __restrict__ out, int B)
{
  __shared__ char xring[2 * BUF_BYTES];   // 34816 B -> 4 blocks/CU
  const int lane = threadIdx.x & 63;
  const int g = lane >> 4;   // k-group / D-row group
  const int c = lane & 15;   // batch col (B,D) == weight row (A)
  const int rowbase = blockIdx.x * 16;

  // ---- A-fragment weights, register-resident (interleaved phi placement:
  //      even elements <- f0[j], odd elements <- f1[j]).
  half8 wih[2][7];    // W_ih[16nt+c][phi_ih(kb,g,e)]
  half8 whh[4][7];    // W_hh[16nt+c][phi(kb,g,e)]
  float4_t bias[7];   // (b_ih+b_hh)[16nt+4g+v]

  #pragma unroll
  for (int nt = 0; nt < 7; ++nt) {
    int nb = nt * 16 + 4 * g;
    float4_t bi = {0.f, 0.f, 0.f, 0.f};
    if (nb + 3 < 100) {
      float4_t a = *(const float4_t*)(b_ih + nb);
      float4_t b = *(const float4_t*)(b_hh + nb);
      bi = a + b;
    }
    bias[nt] = bi;

    int nrow = nt * 16 + c;
    bool rv = (nrow < 100);
    #pragma unroll
    for (int kb = 0; kb < 2; ++kb) {
      float4_t f0 = {0.f,0.f,0.f,0.f}, f1 = {0.f,0.f,0.f,0.f};
      if (rv) {
        const float* p = W_ih + nrow * 64 + kb * 32 + g * 8;
        f0 = *(const float4_t*)p;
        f1 = *(const float4_t*)(p + 4);
      }
      half8 h;
      #pragma unroll
      for (int j = 0; j < 4; ++j) {
        h[2 * j]     = (_Float16)f0[j];   // e even: k = 32kb+8g+j
        h[2 * j + 1] = (_Float16)f1[j];   // e odd : k = 32kb+8g+j+4
      }
      wih[kb][nt] = h;
    }
    #pragma unroll
    for (int kb = 0; kb < 4; ++kb) {
      int clo = kb * 32 + 4 * g;
      int chi = clo + 16;
      float4_t f0 = {0.f,0.f,0.f,0.f}, f1 = {0.f,0.f,0.f,0.f};
      if (rv && clo + 3 < 100) f0 = *(const float4_t*)(W_hh + nrow * 100 + clo);
      if (rv && chi + 3 < 100) f1 = *(const float4_t*)(W_hh + nrow * 100 + chi);
      half8 h;
      #pragma unroll
      for (int j = 0; j < 4; ++j) {
        h[2 * j]     = (_Float16)f0[j];   // e even: h-dim 32kb+4g+j     (acc nt=2kb)
        h[2 * j + 1] = (_Float16)f1[j];   // e odd : h-dim 32kb+16+4g+j (acc nt=2kb+1)
      }
      whh[kb][nt] = h;
    }
  }

  // ---- x slab DMA: lane reads 16B at (row rowbase+j, byte slab*1024+lane*16)
  const float* srcl = x + (size_t)rowbase * 4096 + lane * 4;
  issue_slab(srcl, 0, xring);
  issue_slab(srcl, 1, xring + BUF_BYTES);

  const unsigned ring_base =
      (unsigned)(uintptr_t)(__attribute__((address_space(3))) char*)xring;
  const unsigned xa0 = ring_base + (unsigned)(c * ROW_BYTES + g * 32);

  float4_t acc[7];
  half8 hfrag[4];
  #pragma unroll
  for (int kb = 0; kb < 4; ++kb) hfrag[kb] = (half8)(_Float16)0.0f;  // h_0 = 0

  for (int grp = 0; grp < 16; ++grp) {
    // slab grp landed once only the 16 newer DMAs remain in flight
    asm volatile("s_waitcnt vmcnt(16)" ::: "memory");
    unsigned xg = xa0 + (unsigned)((grp & 1) * BUF_BYTES);

    #pragma unroll
    for (int t4 = 0; t4 < 4; ++t4) {
      // issue x reads for this step (no wait yet)
      unsigned xs = xg + (unsigned)(t4 * 256);
      float4_t s0, s1, s2, s3;
      asm volatile(
          "ds_read_b128 %0, %4 offset:0\n\t"
          "ds_read_b128 %1, %4 offset:16\n\t"
          "ds_read_b128 %2, %4 offset:128\n\t"
          "ds_read_b128 %3, %4 offset:144"
          : "=&v"(s0), "=&v"(s1), "=&v"(s2), "=&v"(s3)
          : "v"(xs) : "memory");

      // recurrence (register-fed; runs while ds_reads are in flight)
      #pragma unroll
      for (int nt = 0; nt < 7; ++nt)
        acc[nt] = __builtin_amdgcn_mfma_f32_16x16x32_f16(whh[0][nt], hfrag[0], bias[nt], 0, 0, 0);
      #pragma unroll
      for (int kb = 1; kb < 4; ++kb)
        #pragma unroll
        for (int nt = 0; nt < 7; ++nt)
          acc[nt] = __builtin_amdgcn_mfma_f32_16x16x32_f16(whh[kb][nt], hfrag[kb], acc[nt], 0, 0, 0);

      // now require the x data
      asm volatile("s_waitcnt lgkmcnt(0)"
                   : "+v"(s0), "+v"(s1), "+v"(s2), "+v"(s3) :: "memory");
      __builtin_amdgcn_sched_barrier(0);

      // x B-frags via pkrtz (phi_ih interleave: pair (s0[j], s1[j]))
      half8 xb0 = pack4(pk2(s0[0], s1[0]), pk2(s0[1], s1[1]),
                        pk2(s0[2], s1[2]), pk2(s0[3], s1[3]));
      half8 xb1 = pack4(pk2(s2[0], s3[0]), pk2(s2[1], s3[1]),
                        pk2(s2[2], s3[2]), pk2(s2[3], s3[3]));
      #pragma unroll
      for (int nt = 0; nt < 7; ++nt) {
        acc[nt] = __builtin_amdgcn_mfma_f32_16x16x32_f16(wih[0][nt], xb0, acc[nt], 0, 0, 0);
        acc[nt] = __builtin_amdgcn_mfma_f32_16x16x32_f16(wih[1][nt], xb1, acc[nt], 0, 0, 0);
      }

      // h_{t+1} = tanh(preact); D regs -> B-frag via 16 pkrtz
      #pragma unroll
      for (int nt = 0; nt < 7; ++nt)
        #pragma unroll
        for (int v = 0; v < 4; ++v)
          acc[nt][v] = tanh_fast(acc[nt][v]);

      #pragma unroll
      for (int kb = 0; kb < 3; ++kb)
        hfrag[kb] = pack4(pk2(acc[2*kb][0], acc[2*kb+1][0]),
                          pk2(acc[2*kb][1], acc[2*kb+1][1]),
                          pk2(acc[2*kb][2], acc[2*kb+1][2]),
                          pk2(acc[2*kb][3], acc[2*kb+1][3]));
      hfrag[3] = pack4(pk2(acc[6][0], 0.0f), pk2(acc[6][1], 0.0f),
                       pk2(acc[6][2], 0.0f), pk2(acc[6][3], 0.0f));
    }

    // refill the buffer we just finished reading (clamped tail keeps cadence)
    int sl = grp + 2; if (sl > 15) sl = 15;
    issue_slab(srcl, sl, xring + (grp & 1) * BUF_BYTES);
  }

  // ---- epilogue: z = tanh(h_last); out = z @ fc_W^T + fc_b (phi-permuted)
  #pragma unroll
  for (int nt = 0; nt < 7; ++nt)
    #pragma unroll
    for (int v = 0; v < 4; ++v)
      acc[nt][v] = tanh_fast(acc[nt][v]);

  half8 zf[4];
  #pragma unroll
  for (int kb = 0; kb < 3; ++kb)
    zf[kb] = pack4(pk2(acc[2*kb][0], acc[2*kb+1][0]),
                   pk2(acc[2*kb][1], acc[2*kb+1][1]),
                   pk2(acc[2*kb][2], acc[2*kb+1][2]),
                   pk2(acc[2*kb][3], acc[2*kb+1][3]));
  zf[3] = pack4(pk2(acc[6][0], 0.0f), pk2(acc[6][1], 0.0f),
                pk2(acc[6][2], 0.0f), pk2(acc[6][3], 0.0f));

  half8 wfc[4][3];
  float4_t bfc[3];
  #pragma unroll
  for (int nt = 0; nt < 3; ++nt) {
    int nb = nt * 16 + 4 * g;
    float4_t bi = {0.f,0.f,0.f,0.f};
    if (nb + 3 < 40) bi = *(const float4_t*)(fc_b + nb);
    bfc[nt] = bi;

    int nrow = nt * 16 + c;
    bool rv = (nrow < 40);
    #pragma unroll
    for (int kb = 0; kb < 4; ++kb) {
      int clo = kb * 32 + 4 * g;
      int chi = clo + 16;
      float4_t f0 = {0.f,0.f,0.f,0.f}, f1 = {0.f,0.f,0.f,0.f};
      if (rv && clo + 3 < 100) f0 = *(const float4_t*)(fc_W + nrow * 100 + clo);
      if (rv && chi + 3 < 100) f1 = *(const float4_t*)(fc_W + nrow * 100 + chi);
      half8 h;
      #pragma unroll
      for (int j = 0; j < 4; ++j) {
        h[2 * j]     = (_Float16)f0[j];
        h[2 * j + 1] = (_Float16)f1[j];
      }
      wfc[kb][nt] = h;
    }
  }

  float4_t oacc[3];
  #pragma unroll
  for (int nt = 0; nt < 3; ++nt) oacc[nt] = bfc[nt];
  #pragma unroll
  for (int kb = 0; kb < 4; ++kb)
    #pragma unroll
    for (int nt = 0; nt < 3; ++nt)
      oacc[nt] = __builtin_amdgcn_mfma_f32_16x16x32_f16(wfc[kb][nt], zf[kb], oacc[nt], 0, 0, 0);

  // store: lane (g,c) holds out[rowbase+c][n = 16nt+4g+v]
  #pragma unroll
  for (int nt = 0; nt < 3; ++nt)
    #pragma unroll
    for (int v = 0; v < 4; ++v) {
      int n = nt * 16 + 4 * g + v;
      if (n < 40)
        out[(size_t)(rowbase + c) * 40 + n] = oacc[nt][v];
    }
}

extern "C" void kernel_launch(void* const* d_in, const int* in_sizes, int n_in,
                              void* d_out, int out_size, void* d_ws, size_t ws_size,
                              hipStream_t stream) {
  const float* x    = (const float*)d_in[0];
  const float* W_ih = (const float*)d_in[1];
  const float* W_hh = (const float*)d_in[2];
  const float* b_ih = (const float*)d_in[3];
  const float* b_hh = (const float*)d_in[4];
  const float* fc_W = (const float*)d_in[5];
  const float* fc_b = (const float*)d_in[6];
  float* outp = (float*)d_out;

  int B = in_sizes[0] / 4096;      // 16384
  int grid = (B + 15) / 16;        // one 16-row tile per 1-wave block
  rnn_fused<<<grid, 64, 0, stream>>>(x, W_ih, W_hh, b_ih, b_hh, fc_W, fc_b, outp, B);
}